// Round 6
// baseline (604.914 us; speedup 1.0000x reference)
//
#include <hip/hip_runtime.h>
#include <hip/hip_bf16.h>

// N=1e6 nodes, V=6e5 var nodes, H=128.
constexpr int H = 128;
constexpr int V = 600000;
constexpr int NTOT = 1000000;

typedef short bf16x8 __attribute__((ext_vector_type(8)));   // 8 bf16 = 4 VGPR
typedef float f32x4 __attribute__((ext_vector_type(4)));

__device__ inline short f2bf(float f) {  // round-to-nearest-even bf16
    unsigned u = __float_as_uint(f);
    u += 0x7FFF + ((u >> 16) & 1);
    return (short)(u >> 16);
}

// uc[h]=u, uc[128+h]=c :  logits[i][h] = vf_i . W1[:,h] + llr_i*u[h] + c[h]
// uc[256..383]=W_llr, uc[384..511]=b_llr
__global__ void precompute_uc_kernel(const float* __restrict__ W_llr,
                                     const float* __restrict__ b_llr,
                                     const float* __restrict__ W_gate,
                                     const float* __restrict__ b_gate,
                                     float* __restrict__ uc) {
    int h = threadIdx.x;  // 128 threads
    float u = 0.0f, c = 0.0f;
    for (int k = 0; k < H; ++k) {
        float w2 = W_gate[(size_t)(H + k) * H + h];
        u += W_llr[k] * w2;
        c += b_llr[k] * w2;
    }
    uc[h] = u;
    uc[H + h] = c + b_gate[h];
    uc[2 * H + h] = W_llr[h];
    uc[3 * H + h] = b_llr[h];
}

// LDS: W1^T only, bf16, 128 n-rows x 256 B, XOR-swizzled 16B granules:
// logical element (n, k) lives at byte n*256 + (((k>>3) ^ (n&15))<<4) + (k&7)*2.
// Read of a b128 granule set is uniform 8 words/bank -> conflict-free.
#define LDS_BYTES 32768

__global__ __launch_bounds__(256, 4) void fused_residual_llr_kernel(
    const float* __restrict__ nf,      // [N][H]
    const float* __restrict__ llr,     // [V]
    const float* __restrict__ W_gate,  // [2H][H]
    const float* __restrict__ uc,      // [4H]
    float* __restrict__ out) {         // [N][H]
    int b = blockIdx.x;
    int tid = threadIdx.x;

    if ((b & 3) == 3) {
        // ---- copy role: rows V..N. 20 sweeps x 4 independent pairs, exact.
        size_t base = (size_t)V * H;
        const float4* src = reinterpret_cast<const float4*>(nf + base);
        float4* dst = reinterpret_cast<float4*>(out + base);
        size_t i0 = (size_t)(b >> 2) * 256 + tid;
        const size_t stride = 625u * 256u;  // 160000; 12.8M/160000 = 80 = 20x4
#pragma unroll 1
        for (int s = 0; s < 20; ++s) {
            size_t i = i0 + (size_t)s * (stride * 4);
            float4 v0 = src[i];
            float4 v1 = src[i + stride];
            float4 v2 = src[i + 2 * stride];
            float4 v3 = src[i + 3 * stride];
            dst[i] = v0;
            dst[i + stride] = v1;
            dst[i + 2 * stride] = v2;
            dst[i + 3 * stride] = v3;
        }
        return;
    }
    int cb = (b >> 2) * 3 + (b & 3);  // compute-block index 0..1874

    __shared__ __align__(16) char lds[LDS_BYTES];

    // ---- one-time: stage W1^T bf16, swizzled ----
#pragma unroll 4
    for (int j = 0; j < 16; ++j) {  // 4096 float4 of W1
        int idx = tid + 256 * j;
        int k = idx >> 5, c4 = idx & 31;
        float4 wv = reinterpret_cast<const float4*>(W_gate)[(size_t)k * 32 + c4];
        float wa[4] = {wv.x, wv.y, wv.z, wv.w};
#pragma unroll
        for (int e = 0; e < 4; ++e) {
            int n = c4 * 4 + e;
            int byteoff = n * 256 + (((k >> 3) ^ (n & 15)) << 4) + (k & 7) * 2;
            *reinterpret_cast<short*>(lds + byteoff) = f2bf(wa[e]);
        }
    }
    __syncthreads();  // the ONLY barrier; no per-tile barriers below

    int lane = tid & 63;
    int w = tid >> 6;          // wave 0..3
    int l15 = lane & 15;
    int l4 = lane >> 4;

    // per-column constants held in VGPRs (col = nfr*16 + l15)
    float u_r[8], c_r[8], wl_r[8], bl_r[8];
#pragma unroll
    for (int nfr = 0; nfr < 8; ++nfr) {
        int col = nfr * 16 + l15;
        u_r[nfr]  = uc[col];
        c_r[nfr]  = uc[128 + col];
        wl_r[nfr] = uc[256 + col];
        bl_r[nfr] = uc[384 + col];
    }

    // ---- 5 independent 16-row stripes per wave, no inter-wave coupling ----
#pragma unroll 1
    for (int t = 0; t < 5; ++t) {
        int rowBase = cb * 320 + (t * 4 + w) * 16;

        // A-frag loads straight from global: lane reads row l15,
        // elements kk*32 + l4*8 .. +7  (two dwordx4 per kk).
        const float4* arow =
            reinterpret_cast<const float4*>(nf + (size_t)(rowBase + l15) * H);
        float4 af[8];
#pragma unroll
        for (int kk = 0; kk < 4; ++kk) {
            af[kk * 2]     = arow[kk * 8 + l4 * 2];
            af[kk * 2 + 1] = arow[kk * 8 + l4 * 2 + 1];
        }
        float llr_r[4];
#pragma unroll
        for (int reg = 0; reg < 4; ++reg)
            llr_r[reg] = llr[rowBase + l4 * 4 + reg];

        // pack f32 -> bf16 fragments
        bf16x8 aF[4];
#pragma unroll
        for (int kk = 0; kk < 4; ++kk) {
            float v8[8] = {af[kk * 2].x,     af[kk * 2].y,
                           af[kk * 2].z,     af[kk * 2].w,
                           af[kk * 2 + 1].x, af[kk * 2 + 1].y,
                           af[kk * 2 + 1].z, af[kk * 2 + 1].w};
            bf16x8 r;
#pragma unroll
            for (int jj = 0; jj < 8; ++jj) r[jj] = f2bf(v8[jj]);
            aF[kk] = r;
        }

        f32x4 acc[8];
#pragma unroll
        for (int nfr = 0; nfr < 8; ++nfr) acc[nfr] = (f32x4){0.f, 0.f, 0.f, 0.f};

#pragma unroll
        for (int kk = 0; kk < 4; ++kk) {
            int gbase = ((kk * 4 + l4) ^ l15) << 4;  // swizzled granule
#pragma unroll
            for (int nfr = 0; nfr < 8; ++nfr) {
                bf16x8 Bf = *reinterpret_cast<const bf16x8*>(
                    lds + (nfr * 16 + l15) * 256 + gbase);
                acc[nfr] = __builtin_amdgcn_mfma_f32_16x16x32_bf16(
                    aF[kk], Bf, acc[nfr], 0, 0, 0);
            }
        }

        // epilogue: C/D lane layout row = l4*4+reg, col = nfr*16+l15.
        // vf re-loaded from global (L2-hit; A-frag regs are k-chunked, unusable).
#pragma unroll
        for (int nfr = 0; nfr < 8; ++nfr) {
#pragma unroll
            for (int reg = 0; reg < 4; ++reg) {
                int row = rowBase + l4 * 4 + reg;
                int col = nfr * 16 + l15;
                float x = acc[nfr][reg] + fmaf(llr_r[reg], u_r[nfr], c_r[nfr]);
                float g = 1.0f / (1.0f + __expf(-x));
                float vf = nf[(size_t)row * H + col];
                float lf = fmaf(llr_r[reg], wl_r[nfr], bl_r[nfr]);
                out[(size_t)row * H + col] = fmaf(g, lf - vf, vf);
            }
        }
    }
}

extern "C" void kernel_launch(void* const* d_in, const int* in_sizes, int n_in,
                              void* d_out, int out_size, void* d_ws, size_t ws_size,
                              hipStream_t stream) {
    const float* nf     = (const float*)d_in[0];
    const float* llr    = (const float*)d_in[1];
    const float* W_llr  = (const float*)d_in[2];
    const float* b_llr  = (const float*)d_in[3];
    const float* W_gate = (const float*)d_in[4];
    const float* b_gate = (const float*)d_in[5];
    float* out = (float*)d_out;
    float* uc  = (float*)d_ws;  // 512 floats: u, c, W_llr, b_llr

    precompute_uc_kernel<<<1, 128, 0, stream>>>(W_llr, b_llr, W_gate, b_gate, uc);

    // 1875 compute blocks (4 waves x 5 stripes x 16 rows = 320 rows each,
    // 1875*320 = 600000 exactly) + 625 copy blocks, interleaved b&3==3.
    fused_residual_llr_kernel<<<2500, 256, 0, stream>>>(nf, llr, W_gate, uc, out);
}

// Round 7
// 246.431 us; speedup vs baseline: 2.4547x; 2.4547x over previous
//
#include <hip/hip_runtime.h>
#include <hip/hip_bf16.h>

// N=1e6 nodes, V=6e5 var nodes, H=128.
constexpr int H = 128;
constexpr int V = 600000;
constexpr int NTOT = 1000000;

typedef short bf16x8 __attribute__((ext_vector_type(8)));   // 8 bf16 = 4 VGPR
typedef float f32x4 __attribute__((ext_vector_type(4)));
typedef unsigned int u32;

__device__ __forceinline__ short f2bf(float f) {  // RNE bf16
    unsigned u = __float_as_uint(f);
    u += 0x7FFF + ((u >> 16) & 1);
    return (short)(u >> 16);
}

// async global->LDS, 16B per lane; ldsDst is the WAVE-UNIFORM base,
// HW writes lane i at ldsDst + i*16 (guide §5 / m97).
__device__ __forceinline__ void async_copy16(char* ldsDst, const float* gSrc) {
    __builtin_amdgcn_global_load_lds(
        (const __attribute__((address_space(1))) u32*)gSrc,
        (__attribute__((address_space(3))) u32*)ldsDst, 16, 0, 0);
}

// uc[h]=u, uc[128+h]=c :  logits[i][h] = vf_i . W1[:,h] + llr_i*u[h] + c[h]
// uc[256..383]=W_llr, uc[384..511]=b_llr
__global__ void precompute_uc_kernel(const float* __restrict__ W_llr,
                                     const float* __restrict__ b_llr,
                                     const float* __restrict__ W_gate,
                                     const float* __restrict__ b_gate,
                                     float* __restrict__ uc) {
    int h = threadIdx.x;  // 128 threads
    float u = 0.0f, c = 0.0f;
    for (int k = 0; k < H; ++k) {
        float w2 = W_gate[(size_t)(H + k) * H + h];
        u += W_llr[k] * w2;
        c += b_llr[k] * w2;
    }
    uc[h] = u;
    uc[H + h] = c + b_gate[h];
    uc[2 * H + h] = W_llr[h];
    uc[3 * H + h] = b_llr[h];
}

// LDS 32 KB total:
//   prologue: W1^T bf16, n*256 + k*2 (n=0..127) — read once into B-frag VGPRs
//   main loop: two 16 KB A-tile buffers (32 rows x 512 B fp32).
//   A swizzle (both-sides involution, rule 21): LDS[row][g'] holds global
//   granule g = g' ^ (row&7); reads apply the same XOR. gload_lds dest stays
//   linear; the SOURCE address is pre-swizzled (per-lane global addr is free).
#define LDS_BYTES 32768
#define ABUF 16384

__global__ __launch_bounds__(256, 4) void fused_residual_llr_kernel(
    const float* __restrict__ nf,      // [N][H]
    const float* __restrict__ llr,     // [V]
    const float* __restrict__ W_gate,  // [2H][H]
    const float* __restrict__ uc,      // [4H]
    float* __restrict__ out) {         // [N][H]
    int b = blockIdx.x;
    int tid = threadIdx.x;

    if ((b & 3) == 3) {
        // ---- copy role: rows V..N. 250 blocks, 50 sweeps x 4 pairs, exact.
        size_t base = (size_t)V * H;
        const float4* src = reinterpret_cast<const float4*>(nf + base);
        float4* dst = reinterpret_cast<float4*>(out + base);
        size_t i0 = (size_t)(b >> 2) * 256 + tid;
        const size_t stride = 250u * 256u;  // 64000; 12.8M/64000 = 200 = 50x4
#pragma unroll 1
        for (int s = 0; s < 50; ++s) {
            size_t i = i0 + (size_t)s * (stride * 4);
            float4 v0 = src[i];
            float4 v1 = src[i + stride];
            float4 v2 = src[i + 2 * stride];
            float4 v3 = src[i + 3 * stride];
            dst[i] = v0;
            dst[i + stride] = v1;
            dst[i + 2 * stride] = v2;
            dst[i + 3 * stride] = v3;
        }
        return;
    }
    int cb = (b >> 2) * 3 + (b & 3);  // compute-block index 0..749

    __shared__ __align__(16) char lds[LDS_BYTES];

    int lane = tid & 63;
    int w = tid >> 6;          // wave 0..3; wave owns cols [w*32, w*32+32)
    int l15 = lane & 15;
    int l4 = lane >> 4;

    // ---- prologue: stage W1^T bf16 (linear n*256 + k*2) ----
#pragma unroll 4
    for (int j = 0; j < 16; ++j) {  // 4096 float4 of W1
        int idx = tid + 256 * j;
        int k = idx >> 5, c4 = idx & 31;
        float4 wv = reinterpret_cast<const float4*>(W_gate)[(size_t)k * 32 + c4];
        float wa[4] = {wv.x, wv.y, wv.z, wv.w};
#pragma unroll
        for (int e = 0; e < 4; ++e) {
            int n = c4 * 4 + e;
            *reinterpret_cast<short*>(lds + n * 256 + k * 2) = f2bf(wa[e]);
        }
    }
    // per-column constants -> VGPRs (tiny, L2-broadcast reads)
    float u_r[2], c_r[2], wl_r[2], bl_r[2];
#pragma unroll
    for (int nfr = 0; nfr < 2; ++nfr) {
        int col = w * 32 + nfr * 16 + l15;
        u_r[nfr]  = uc[col];
        c_r[nfr]  = uc[128 + col];
        wl_r[nfr] = uc[256 + col];
        bl_r[nfr] = uc[384 + col];
    }
    __syncthreads();

    // B fragments (held in VGPRs for all 25 tiles): B[k][n] = W1^T[n][k]
    bf16x8 Bf[4][2];
#pragma unroll
    for (int kk = 0; kk < 4; ++kk)
#pragma unroll
        for (int nfr = 0; nfr < 2; ++nfr) {
            int n = w * 32 + nfr * 16 + l15;
            Bf[kk][nfr] = *reinterpret_cast<const bf16x8*>(
                lds + n * 256 + kk * 64 + l4 * 16);
        }
    __syncthreads();  // all B reads done before A-tiles overwrite W region

    int rowBase0 = cb * 800;  // 25 tiles x 32 rows

    // STAGE tile0 -> buf0. Per wave: 4 instrs x 1 KB linear LDS.
    // Source granule pre-swizzled: g = (lane&31) ^ (row&7).
#pragma unroll
    for (int j = 0; j < 4; ++j) {
        int rl = (w * 4 + j) * 2 + (lane >> 5);
        int gg = (lane & 31) ^ (rl & 7);
        async_copy16(lds + (w * 4 + j) * 1024,
                     nf + (size_t)(rowBase0 + rl) * H + gg * 4);
    }

    int cur = 0;
#pragma unroll 1
    for (int t = 0; t < 25; ++t) {
        int rowBase = rowBase0 + t * 32;
        __syncthreads();  // vmcnt(0)+barrier: tile t staged & visible

        // (a) issue STAGE for t+1 immediately — flies under all of t's work
        if (t < 24) {
            char* nbuf = lds + (cur ^ 1) * ABUF;
            int rowN = rowBase + 32;
#pragma unroll
            for (int j = 0; j < 4; ++j) {
                int rl = (w * 4 + j) * 2 + (lane >> 5);
                int gg = (lane & 31) ^ (rl & 7);
                async_copy16(nbuf + (w * 4 + j) * 1024,
                             nf + (size_t)(rowN + rl) * H + gg * 4);
            }
        }
        // llr for this tile's rows (L2/L3-resident, 8 lanes share each)
        float llr_r[8];
#pragma unroll
        for (int rg = 0; rg < 2; ++rg)
#pragma unroll
            for (int reg = 0; reg < 4; ++reg)
                llr_r[rg * 4 + reg] = llr[rowBase + rg * 16 + l4 * 4 + reg];

        // (b) MFMA from buf[cur]: fp32 ds_read (swizzled) -> bf16 -> mfma
        char* buf = lds + cur * ABUF;
        f32x4 acc[2][2];
#pragma unroll
        for (int rg = 0; rg < 2; ++rg)
#pragma unroll
            for (int nfr = 0; nfr < 2; ++nfr)
                acc[rg][nfr] = (f32x4){0.f, 0.f, 0.f, 0.f};

#pragma unroll
        for (int kk = 0; kk < 4; ++kk) {
#pragma unroll
            for (int rg = 0; rg < 2; ++rg) {
                int rl = rg * 16 + l15;     // A row; k = kk*32 + l4*8 + j
                int g0 = (l4 * 2) ^ (l15 & 7);
                const char* base = buf + rl * 512 + kk * 128;
                f32x4 lo = *reinterpret_cast<const f32x4*>(base + (g0 << 4));
                f32x4 hi = *reinterpret_cast<const f32x4*>(base + ((g0 ^ 1) << 4));
                bf16x8 a;
                a[0] = f2bf(lo[0]); a[1] = f2bf(lo[1]);
                a[2] = f2bf(lo[2]); a[3] = f2bf(lo[3]);
                a[4] = f2bf(hi[0]); a[5] = f2bf(hi[1]);
                a[6] = f2bf(hi[2]); a[7] = f2bf(hi[3]);
                acc[rg][0] = __builtin_amdgcn_mfma_f32_16x16x32_bf16(
                    a, Bf[kk][0], acc[rg][0], 0, 0, 0);
                acc[rg][1] = __builtin_amdgcn_mfma_f32_16x16x32_bf16(
                    a, Bf[kk][1], acc[rg][1], 0, 0, 0);
            }
        }

        // (c) epilogue: vf from LDS (exact fp32), gate, blend, store
#pragma unroll
        for (int rg = 0; rg < 2; ++rg) {
#pragma unroll
            for (int reg = 0; reg < 4; ++reg) {
                int rl = rg * 16 + l4 * 4 + reg;   // C/D row = (lane>>4)*4+reg
                float lr = llr_r[rg * 4 + reg];
#pragma unroll
                for (int nfr = 0; nfr < 2; ++nfr) {
                    int col = w * 32 + nfr * 16 + l15;  // C/D col = lane&15
                    float x = acc[rg][nfr][reg] + fmaf(lr, u_r[nfr], c_r[nfr]);
                    float g = 1.0f / (1.0f + __expf(-x));
                    int gcol = w * 8 + nfr * 4 + (l15 >> 2);
                    float vf = *reinterpret_cast<const float*>(
                        buf + rl * 512 + ((gcol ^ (rl & 7)) << 4) + (l15 & 3) * 4);
                    float lf = fmaf(lr, wl_r[nfr], bl_r[nfr]);
                    out[(size_t)(rowBase + rl) * H + col] = fmaf(g, lf - vf, vf);
                }
            }
        }
        cur ^= 1;
    }
}

extern "C" void kernel_launch(void* const* d_in, const int* in_sizes, int n_in,
                              void* d_out, int out_size, void* d_ws, size_t ws_size,
                              hipStream_t stream) {
    const float* nf     = (const float*)d_in[0];
    const float* llr    = (const float*)d_in[1];
    const float* W_llr  = (const float*)d_in[2];
    const float* b_llr  = (const float*)d_in[3];
    const float* W_gate = (const float*)d_in[4];
    const float* b_gate = (const float*)d_in[5];
    float* out = (float*)d_out;
    float* uc  = (float*)d_ws;  // 512 floats: u, c, W_llr, b_llr

    precompute_uc_kernel<<<1, 128, 0, stream>>>(W_llr, b_llr, W_gate, b_gate, uc);

    // 750 compute blocks (25 tiles x 32 rows = 800 rows each; 750*800 = 600000
    // exactly) + 250 copy blocks, interleaved b&3==3. Grid = 1000 blocks ->
    // fully resident at 4 blocks/CU (LDS 32 KB, VGPR <=128).
    fused_residual_llr_kernel<<<1000, 256, 0, stream>>>(nf, llr, W_gate, uc, out);
}